// Round 8
// baseline (298.801 us; speedup 1.0000x reference)
//
#include <hip/hip_runtime.h>
#include <math.h>

// Problem constants (match reference)
constexpr int B    = 4;
constexpr int N    = 32768;   // 2^15
constexpr int K    = 16;
constexpr int CIN  = 32;
constexpr int H    = 32;
constexpr int COUT = 32;
constexpr int NODES = B * N;            // 131072
constexpr int E      = B * N * K;       // 2097152 edges

// Bucketing: one bucket per 64 dst nodes == one gather block
constexpr int BPB        = 512;          // buckets per batch (N/64)
constexpr int NBUCKETS   = B * BPB;      // 2048
constexpr int BUCKET_CAP = 2048;         // mean 1024, sigma 32 -> huge headroom
constexpr int BIN_EDGES  = 8192;         // edges per bin block
constexpr int BIN_BLOCKS = E / BIN_EDGES;       // 256 (64 per batch)

// ---------------------------------------------------------------------------
// Kernel 1: fc1 + fold grid_weight and gaussian normalizer into hh[node][h]
//   hh[node,h] = coef[h] * gw[node] * (sum_c x[b,c,n]*W1[h,c] + b1[h])
// ---------------------------------------------------------------------------
__global__ __launch_bounds__(256) void k_fc1(const float* __restrict__ x,
                                             const float* __restrict__ grid_weight,
                                             const float* __restrict__ W1,
                                             const float* __restrict__ b1,
                                             const float* __restrict__ baseweight,
                                             float* __restrict__ hh)
{
    __shared__ float sW1[H * CIN];
    __shared__ float sb1[H];
    __shared__ float scoef[H];
    const int tid = threadIdx.x;
    for (int i = tid; i < H * CIN; i += 256) sW1[i] = W1[i];
    if (tid < H) {
        sb1[tid] = b1[tid];
        float t = baseweight[tid] * (float)(1.0 / M_PI);
        scoef[tid] = t * sqrtf(t);           // (bw/pi)^1.5
    }
    __syncthreads();

    const int node = blockIdx.x * 256 + tid;
    const int b = node >> 15;
    const int n = node & (N - 1);
    const float* xb = x + (size_t)b * CIN * N + n;

    float acc[H];
#pragma unroll
    for (int h = 0; h < H; ++h) acc[h] = sb1[h];
#pragma unroll
    for (int c = 0; c < CIN; ++c) {
        float xv = xb[(size_t)c * N];
#pragma unroll
        for (int h = 0; h < H; ++h) acc[h] = fmaf(xv, sW1[h * CIN + c], acc[h]);
    }
    const float gw = grid_weight[node];

    float4* dst = (float4*)(hh + (size_t)node * H);
#pragma unroll
    for (int i = 0; i < H / 4; ++i) {
        float4 v;
        v.x = acc[4 * i + 0] * gw * scoef[4 * i + 0];
        v.y = acc[4 * i + 1] * gw * scoef[4 * i + 1];
        v.z = acc[4 * i + 2] * gw * scoef[4 * i + 2];
        v.w = acc[4 * i + 3] * gw * scoef[4 * i + 3];
        dst[i] = v;
    }
}

// ---------------------------------------------------------------------------
// k_bin: LDS counting-sort of 8192 edges into 512 dst-buckets, then
// line-granular run flushes to global bucket regions. Replaces the whole
// global hist/scan/scatter CSR build.
// Entry payload: ((dst & 63) << 16) | src   (both batch-local, < 32768)
// ---------------------------------------------------------------------------
__global__ __launch_bounds__(256) void k_bin(const int* __restrict__ esrc,
                                             const int* __restrict__ edst,
                                             int* __restrict__ gcur,
                                             unsigned* __restrict__ gbucket)
{
    __shared__ int hist[BPB];
    __shared__ int lbase[BPB];
    __shared__ int cur[BPB];
    __shared__ int sc[256];
    __shared__ unsigned staged[BIN_EDGES];   // 32 KB

    const int tid = threadIdx.x;
    const int e0  = blockIdx.x * BIN_EDGES;
    const int batch = blockIdx.x >> 6;       // 64 blocks per batch

    hist[2 * tid] = 0;
    hist[2 * tid + 1] = 0;
    __syncthreads();

    // pass 1: histogram over dst>>6
#pragma unroll 4
    for (int i = 0; i < BIN_EDGES / 256; ++i) {
        const int d = edst[e0 + i * 256 + tid];
        atomicAdd(&hist[d >> 6], 1);
    }
    __syncthreads();

    // exclusive scan of 512 via pairwise + 256-wide Hillis-Steele
    const int h0 = hist[2 * tid], h1 = hist[2 * tid + 1];
    sc[tid] = h0 + h1;
    __syncthreads();
    for (int off = 1; off < 256; off <<= 1) {
        int v = (tid >= off) ? sc[tid - off] : 0;
        __syncthreads();
        sc[tid] += v;
        __syncthreads();
    }
    const int pairExcl = sc[tid] - (h0 + h1);
    lbase[2 * tid]     = pairExcl;
    lbase[2 * tid + 1] = pairExcl + h0;
    cur[2 * tid]       = pairExcl;
    cur[2 * tid + 1]   = pairExcl + h0;
    __syncthreads();

    // pass 2: place payloads into LDS staging (counting-sort scatter)
#pragma unroll 4
    for (int i = 0; i < BIN_EDGES / 256; ++i) {
        const int idx = e0 + i * 256 + tid;
        const int d = edst[idx];
        const int s = esrc[idx];
        const int pos = atomicAdd(&cur[d >> 6], 1);
        staged[pos] = ((unsigned)(d & 63) << 16) | (unsigned)s;
    }
    __syncthreads();

    // flush runs: wave w handles buckets w, w+4, ... (mean run 16 = 64 B line)
    const int wv   = tid >> 6;
    const int lane = tid & 63;
    for (int bkt = wv; bkt < BPB; bkt += 4) {
        const int cnt = hist[bkt];
        if (cnt == 0) continue;
        int gb0 = 0;
        if (lane == 0) gb0 = atomicAdd(&gcur[batch * BPB + bkt], cnt);
        gb0 = __shfl(gb0, 0, 64);
        unsigned* dstp = gbucket + (size_t)(batch * BPB + bkt) * BUCKET_CAP;
        const int lb = lbase[bkt];
        for (int j = lane; j < cnt; j += 64) {
            const int gi = gb0 + j;
            if (gi < BUCKET_CAP) dstp[gi] = staged[lb + j];
        }
    }
}

// ---------------------------------------------------------------------------
// k_gather2: one block per bucket (= 64 dst nodes). Reads its bucket
// coalesced, LDS counting-sorts by dst&63, then per-node MLP-structured
// gather (phase1: parallel d2; phase2: shfl-broadcast + 4-deep hh loads),
// fc2, transposed coalesced store. ent[] statically indexed -> stays in VGPRs.
// ---------------------------------------------------------------------------
__global__ __launch_bounds__(256) void k_gather2(const float* __restrict__ grid,
                                                 const float* __restrict__ baseweight,
                                                 const float* __restrict__ hh,
                                                 const unsigned* __restrict__ gbucket,
                                                 const int* __restrict__ gcur,
                                                 const float* __restrict__ W2,
                                                 const float* __restrict__ b2,
                                                 float* __restrict__ out)
{
    __shared__ float sW2[COUT][H + 1];
    __shared__ float sb2[COUT];
    __shared__ float sbw[H];
    __shared__ float tmp[8][H + 1];
    __shared__ float stage[64][COUT + 1];
    __shared__ int hist64[64];
    __shared__ int base64[64];
    __shared__ int cur64[64];
    __shared__ unsigned short srt[BUCKET_CAP];   // sorted batch-local src ids

    const int tid = threadIdx.x;
    for (int i = tid; i < COUT * H; i += 256) sW2[i >> 5][i & 31] = W2[i];
    if (tid < COUT) sb2[tid] = b2[tid];
    if (tid < H)    sbw[tid] = baseweight[tid];
    if (tid < 64)   hist64[tid] = 0;
    __syncthreads();

    const int gb    = blockIdx.x;          // bucket id [0, 2048)
    const int batch = gb >> 9;             // 512 buckets per batch
    const int bloc  = gb & (BPB - 1);
    const int bb    = batch * N;           // batch node base
    const int n0    = bloc * 64;           // first dst (batch-local)

    const int cnt = min(gcur[gb], BUCKET_CAP);
    const unsigned* bp = gbucket + (size_t)gb * BUCKET_CAP;

    // pass 1: load entries (coalesced, statically indexed) + histogram
    unsigned ent[BUCKET_CAP / 256];        // 8, static index only
#pragma unroll
    for (int j = 0; j < BUCKET_CAP / 256; ++j) {
        const int i = j * 256 + tid;
        if (i < cnt) {
            ent[j] = bp[i];
            atomicAdd(&hist64[ent[j] >> 16], 1);
        }
    }
    __syncthreads();

    // exclusive scan of 64 (Hillis-Steele, first 64 threads)
    if (tid < 64) base64[tid] = hist64[tid];
    __syncthreads();
    for (int off = 1; off < 64; off <<= 1) {
        int v = 0;
        if (tid < 64 && tid >= off) v = base64[tid - off];
        __syncthreads();
        if (tid < 64) base64[tid] += v;
        __syncthreads();
    }
    if (tid < 64) {
        base64[tid] -= hist64[tid];        // exclusive
        cur64[tid]   = base64[tid];
    }
    __syncthreads();

    // pass 2: place src ids grouped by dst (statically indexed)
#pragma unroll
    for (int j = 0; j < BUCKET_CAP / 256; ++j) {
        const int i = j * 256 + tid;
        if (i < cnt) {
            const int pos = atomicAdd(&cur64[ent[j] >> 16], 1);
            srt[pos] = (unsigned short)(ent[j] & 0xFFFFu);
        }
    }
    __syncthreads();

    const int g    = tid >> 5;             // subgroup 0..7
    const int lane = tid & 31;             // channel
    const float bwl = sbw[lane];

#pragma unroll
    for (int r = 0; r < 8; ++r) {
        const int nl  = g * 8 + r;         // local node 0..63
        const int d   = bb + n0 + nl;      // global dst node
        const int off = base64[nl];
        const int cn  = hist64[nl];
        const float gx = grid[d * 3 + 0];
        const float gy = grid[d * 3 + 1];
        const float gz = grid[d * 3 + 2];

        float acc = 0.0f;
        for (int base = 0; base < cn; base += 32) {
            const int m = min(32, cn - base);

            // phase 1: parallel per-lane src fetch + d2
            int   s_l  = 0;
            float d2_l = 0.0f;
            if (lane < m) {
                s_l = bb + (int)srt[off + base + lane];
                const float dx = grid[s_l * 3 + 0] - gx;
                const float dy = grid[s_l * 3 + 1] - gy;
                const float dz = grid[s_l * 3 + 2] - gz;
                d2_l = dx * dx + dy * dy + dz * dz;
            }

            // phase 2: broadcast, 4-deep independent hh loads
            int i = 0;
            for (; i + 4 <= m; i += 4) {
                const int s0 = __shfl(s_l, i + 0, 32);
                const int s1 = __shfl(s_l, i + 1, 32);
                const int s2 = __shfl(s_l, i + 2, 32);
                const int s3 = __shfl(s_l, i + 3, 32);
                const float w0 = __shfl(d2_l, i + 0, 32);
                const float w1 = __shfl(d2_l, i + 1, 32);
                const float w2 = __shfl(d2_l, i + 2, 32);
                const float w3 = __shfl(d2_l, i + 3, 32);
                const float f0 = hh[(size_t)s0 * H + lane];
                const float f1 = hh[(size_t)s1 * H + lane];
                const float f2 = hh[(size_t)s2 * H + lane];
                const float f3 = hh[(size_t)s3 * H + lane];
                acc = fmaf(__expf(-bwl * w0), f0, acc);
                acc = fmaf(__expf(-bwl * w1), f1, acc);
                acc = fmaf(__expf(-bwl * w2), f2, acc);
                acc = fmaf(__expf(-bwl * w3), f3, acc);
            }
            for (; i < m; ++i) {
                const int   s = __shfl(s_l, i, 32);
                const float w = __shfl(d2_l, i, 32);
                acc = fmaf(__expf(-bwl * w), hh[(size_t)s * H + lane], acc);
            }
        }

        // fc2 for this node (intra-wave lockstep)
        tmp[g][lane] = acc;
        float o_val = sb2[lane];
#pragma unroll
        for (int h = 0; h < H; ++h)
            o_val = fmaf(tmp[g][h], sW2[lane][h], o_val);
        stage[nl][lane] = o_val;
    }
    __syncthreads();

    // coalesced transposed write: out[batch, o, n0..n0+63]
    float* ob = out + (size_t)batch * COUT * N + n0;
#pragma unroll
    for (int i = 0; i < 8; ++i) {
        const int flat = i * 256 + tid;
        const int o = flat >> 6;
        const int j = flat & 63;
        ob[(size_t)o * N + j] = stage[j][o];
    }
}

// ---------------------------------------------------------------------------
extern "C" void kernel_launch(void* const* d_in, const int* in_sizes, int n_in,
                              void* d_out, int out_size, void* d_ws, size_t ws_size,
                              hipStream_t stream)
{
    const float* x    = (const float*)d_in[0];
    const float* grid = (const float*)d_in[1];
    const float* gw   = (const float*)d_in[2];
    const int*   es   = (const int*)d_in[3];
    const int*   ed   = (const int*)d_in[4];
    const float* W1   = (const float*)d_in[5];
    const float* b1   = (const float*)d_in[6];
    const float* W2   = (const float*)d_in[7];
    const float* b2   = (const float*)d_in[8];
    const float* bw   = (const float*)d_in[9];
    float* out = (float*)d_out;

    // workspace: hh 16 MB | gbucket 16 MB | gcur 8 KB   (33.57 MB total)
    char* w = (char*)d_ws;
    float*    hh      = (float*)(w);
    unsigned* gbucket = (unsigned*)(w + (size_t)NODES * H * 4);
    int*      gcur    = (int*)(w + (size_t)NODES * H * 4
                                 + (size_t)NBUCKETS * BUCKET_CAP * 4);

    hipMemsetAsync(gcur, 0, (size_t)NBUCKETS * sizeof(int), stream);

    k_fc1<<<NODES / 256, 256, 0, stream>>>(x, gw, W1, b1, bw, hh);
    k_bin<<<BIN_BLOCKS, 256, 0, stream>>>(es, ed, gcur, gbucket);
    k_gather2<<<NBUCKETS, 256, 0, stream>>>(grid, bw, hh, gbucket, gcur,
                                            W2, b2, out);
}

// Round 9
// 181.933 us; speedup vs baseline: 1.6424x; 1.6424x over previous
//
#include <hip/hip_runtime.h>
#include <math.h>

// Problem constants (match reference)
constexpr int B    = 4;
constexpr int N    = 32768;   // 2^15
constexpr int K    = 16;
constexpr int CIN  = 32;
constexpr int H    = 32;
constexpr int COUT = 32;
constexpr int NODES = B * N;            // 131072
constexpr int E      = B * N * K;       // 2097152 edges

// Bucketing: one bucket per 64 dst nodes == one gather block
constexpr int BPB        = 512;          // buckets per batch (N/64)
constexpr int NBUCKETS   = B * BPB;      // 2048
constexpr int BUCKET_CAP = 2048;         // mean 1024, sigma 32 -> huge headroom
constexpr int BIN_EDGES  = 8192;         // edges per bin block
constexpr int BIN_BLOCKS = E / BIN_EDGES;       // 256 (64 per batch)
constexpr int BIN_THREADS = 1024;        // 16 waves/CU for latency hiding

// ---------------------------------------------------------------------------
// Kernel 1: fc1 + fold grid_weight and gaussian normalizer into hh[node][h]
// ---------------------------------------------------------------------------
__global__ __launch_bounds__(256) void k_fc1(const float* __restrict__ x,
                                             const float* __restrict__ grid_weight,
                                             const float* __restrict__ W1,
                                             const float* __restrict__ b1,
                                             const float* __restrict__ baseweight,
                                             float* __restrict__ hh)
{
    __shared__ float sW1[H * CIN];
    __shared__ float sb1[H];
    __shared__ float scoef[H];
    const int tid = threadIdx.x;
    for (int i = tid; i < H * CIN; i += 256) sW1[i] = W1[i];
    if (tid < H) {
        sb1[tid] = b1[tid];
        float t = baseweight[tid] * (float)(1.0 / M_PI);
        scoef[tid] = t * sqrtf(t);           // (bw/pi)^1.5
    }
    __syncthreads();

    const int node = blockIdx.x * 256 + tid;
    const int b = node >> 15;
    const int n = node & (N - 1);
    const float* xb = x + (size_t)b * CIN * N + n;

    float acc[H];
#pragma unroll
    for (int h = 0; h < H; ++h) acc[h] = sb1[h];
#pragma unroll
    for (int c = 0; c < CIN; ++c) {
        float xv = xb[(size_t)c * N];
#pragma unroll
        for (int h = 0; h < H; ++h) acc[h] = fmaf(xv, sW1[h * CIN + c], acc[h]);
    }
    const float gw = grid_weight[node];

    float4* dst = (float4*)(hh + (size_t)node * H);
#pragma unroll
    for (int i = 0; i < H / 4; ++i) {
        float4 v;
        v.x = acc[4 * i + 0] * gw * scoef[4 * i + 0];
        v.y = acc[4 * i + 1] * gw * scoef[4 * i + 1];
        v.z = acc[4 * i + 2] * gw * scoef[4 * i + 2];
        v.w = acc[4 * i + 3] * gw * scoef[4 * i + 3];
        dst[i] = v;
    }
}

// ---------------------------------------------------------------------------
// k_bin v2: 1024 threads, LDS counting-sort of 8192 edges into 512 buckets,
// flat fully-parallel flush (every thread recovers its entry's bucket from
// the payload and computes its global slot directly).
// Payload: (d_local << 16) | src_local   (both < 32768)
//   bucket = payload >> 22, dst-in-bucket = (payload >> 16) & 63
// ---------------------------------------------------------------------------
__global__ __launch_bounds__(BIN_THREADS) void k_bin(const int* __restrict__ esrc,
                                                     const int* __restrict__ edst,
                                                     int* __restrict__ gcur,
                                                     unsigned* __restrict__ gbucket)
{
    __shared__ int hist[BPB];
    __shared__ int lbase[BPB];
    __shared__ int cur[BPB];
    __shared__ int gbase[BPB];
    __shared__ int sc[256];
    __shared__ unsigned staged[BIN_EDGES];   // 32 KB

    const int tid = threadIdx.x;
    const int e0  = blockIdx.x * BIN_EDGES;
    const int batch = blockIdx.x >> 6;       // 64 blocks per batch

    for (int i = tid; i < BPB; i += BIN_THREADS) hist[i] = 0;
    __syncthreads();

    // pass 1: histogram over dst>>6 (8 edges/thread)
#pragma unroll
    for (int i = 0; i < BIN_EDGES / BIN_THREADS; ++i) {
        const int d = edst[e0 + i * BIN_THREADS + tid];
        atomicAdd(&hist[d >> 6], 1);
    }
    __syncthreads();

    // exclusive scan of 512 (pairwise + 256-wide Hillis-Steele; all threads
    // execute every barrier)
    int h0 = 0, h1 = 0;
    if (tid < 256) {
        h0 = hist[2 * tid];
        h1 = hist[2 * tid + 1];
        sc[tid] = h0 + h1;
    }
    __syncthreads();
    for (int off = 1; off < 256; off <<= 1) {
        int v = 0;
        if (tid < 256 && tid >= off) v = sc[tid - off];
        __syncthreads();
        if (tid < 256) sc[tid] += v;
        __syncthreads();
    }
    if (tid < 256) {
        const int pairExcl = sc[tid] - (h0 + h1);
        lbase[2 * tid]     = pairExcl;
        lbase[2 * tid + 1] = pairExcl + h0;
        cur[2 * tid]       = pairExcl;
        cur[2 * tid + 1]   = pairExcl + h0;
    }
    __syncthreads();

    // acquire all per-bucket global bases in parallel (independent of pass 2)
    if (tid < BPB) gbase[tid] = atomicAdd(&gcur[batch * BPB + tid], hist[tid]);

    // pass 2: place payloads into LDS staging (counting-sort scatter)
#pragma unroll
    for (int i = 0; i < BIN_EDGES / BIN_THREADS; ++i) {
        const int idx = e0 + i * BIN_THREADS + tid;
        const int d = edst[idx];
        const int s = esrc[idx];
        const int pos = atomicAdd(&cur[d >> 6], 1);
        staged[pos] = ((unsigned)d << 16) | (unsigned)s;
    }
    __syncthreads();

    // flat parallel flush: all 1024 threads, coalesced-run writes
    unsigned* gb_batch = gbucket + (size_t)batch * BPB * BUCKET_CAP;
#pragma unroll
    for (int i = 0; i < BIN_EDGES / BIN_THREADS; ++i) {
        const int idx = i * BIN_THREADS + tid;
        const unsigned v = staged[idx];
        const int bkt = (int)(v >> 22);
        const int p = gbase[bkt] + (idx - lbase[bkt]);
        if (p < BUCKET_CAP) gb_batch[(size_t)bkt * BUCKET_CAP + p] = v;
    }
}

// ---------------------------------------------------------------------------
// k_gather2: one block per bucket (= 64 dst nodes), XCD-batch-swizzled so
// each batch's blocks share the 2-XCD L2 pair holding that batch's 4 MB hh
// slice. Reads bucket coalesced, LDS counting-sorts by dst&63, per-node
// MLP-structured gather, fc2, transposed coalesced store.
// ---------------------------------------------------------------------------
__global__ __launch_bounds__(256) void k_gather2(const float* __restrict__ grid,
                                                 const float* __restrict__ baseweight,
                                                 const float* __restrict__ hh,
                                                 const unsigned* __restrict__ gbucket,
                                                 const int* __restrict__ gcur,
                                                 const float* __restrict__ W2,
                                                 const float* __restrict__ b2,
                                                 float* __restrict__ out)
{
    __shared__ float sW2[COUT][H + 1];
    __shared__ float sb2[COUT];
    __shared__ float sbw[H];
    __shared__ float tmp[8][H + 1];
    __shared__ float stage[64][COUT + 1];
    __shared__ int hist64[64];
    __shared__ int base64[64];
    __shared__ int cur64[64];
    __shared__ unsigned short srt[BUCKET_CAP];   // sorted batch-local src ids

    const int tid = threadIdx.x;
    for (int i = tid; i < COUT * H; i += 256) sW2[i >> 5][i & 31] = W2[i];
    if (tid < COUT) sb2[tid] = b2[tid];
    if (tid < H)    sbw[tid] = baseweight[tid];
    if (tid < 64)   hist64[tid] = 0;
    __syncthreads();

    // XCD-batch swizzle: batch from blockIdx bits [2:1] (assumes round-robin
    // XCD assignment). Bijective: bloc = bits[10:3] << 1 | bit0.
    const int bi    = blockIdx.x;
    const int batch = (bi & 7) >> 1;
    const int bloc  = ((bi >> 3) << 1) | (bi & 1);
    const int gb    = batch * BPB + bloc;

    const int bb    = batch * N;           // batch node base
    const int n0    = bloc * 64;           // first dst (batch-local)

    const int cnt = min(gcur[gb], BUCKET_CAP);
    const unsigned* bp = gbucket + (size_t)gb * BUCKET_CAP;

    // pass 1: load entries (coalesced, statically indexed) + histogram
    unsigned ent[BUCKET_CAP / 256];        // 8, static index only
#pragma unroll
    for (int j = 0; j < BUCKET_CAP / 256; ++j) {
        const int i = j * 256 + tid;
        if (i < cnt) {
            ent[j] = bp[i];
            atomicAdd(&hist64[(ent[j] >> 16) & 63], 1);
        }
    }
    __syncthreads();

    // exclusive scan of 64 (Hillis-Steele, first 64 threads)
    if (tid < 64) base64[tid] = hist64[tid];
    __syncthreads();
    for (int off = 1; off < 64; off <<= 1) {
        int v = 0;
        if (tid < 64 && tid >= off) v = base64[tid - off];
        __syncthreads();
        if (tid < 64) base64[tid] += v;
        __syncthreads();
    }
    if (tid < 64) {
        base64[tid] -= hist64[tid];        // exclusive
        cur64[tid]   = base64[tid];
    }
    __syncthreads();

    // pass 2: place src ids grouped by dst (statically indexed)
#pragma unroll
    for (int j = 0; j < BUCKET_CAP / 256; ++j) {
        const int i = j * 256 + tid;
        if (i < cnt) {
            const int pos = atomicAdd(&cur64[(ent[j] >> 16) & 63], 1);
            srt[pos] = (unsigned short)(ent[j] & 0xFFFFu);
        }
    }
    __syncthreads();

    const int g    = tid >> 5;             // subgroup 0..7
    const int lane = tid & 31;             // channel
    const float bwl = sbw[lane];

#pragma unroll
    for (int r = 0; r < 8; ++r) {
        const int nl  = g * 8 + r;         // local node 0..63
        const int d   = bb + n0 + nl;      // global dst node
        const int off = base64[nl];
        const int cn  = hist64[nl];
        const float gx = grid[d * 3 + 0];
        const float gy = grid[d * 3 + 1];
        const float gz = grid[d * 3 + 2];

        float acc = 0.0f;
        for (int base = 0; base < cn; base += 32) {
            const int m = min(32, cn - base);

            // phase 1: parallel per-lane src fetch + d2
            int   s_l  = 0;
            float d2_l = 0.0f;
            if (lane < m) {
                s_l = bb + (int)srt[off + base + lane];
                const float dx = grid[s_l * 3 + 0] - gx;
                const float dy = grid[s_l * 3 + 1] - gy;
                const float dz = grid[s_l * 3 + 2] - gz;
                d2_l = dx * dx + dy * dy + dz * dz;
            }

            // phase 2: broadcast, 4-deep independent hh loads
            int i = 0;
            for (; i + 4 <= m; i += 4) {
                const int s0 = __shfl(s_l, i + 0, 32);
                const int s1 = __shfl(s_l, i + 1, 32);
                const int s2 = __shfl(s_l, i + 2, 32);
                const int s3 = __shfl(s_l, i + 3, 32);
                const float w0 = __shfl(d2_l, i + 0, 32);
                const float w1 = __shfl(d2_l, i + 1, 32);
                const float w2 = __shfl(d2_l, i + 2, 32);
                const float w3 = __shfl(d2_l, i + 3, 32);
                const float f0 = hh[(size_t)s0 * H + lane];
                const float f1 = hh[(size_t)s1 * H + lane];
                const float f2 = hh[(size_t)s2 * H + lane];
                const float f3 = hh[(size_t)s3 * H + lane];
                acc = fmaf(__expf(-bwl * w0), f0, acc);
                acc = fmaf(__expf(-bwl * w1), f1, acc);
                acc = fmaf(__expf(-bwl * w2), f2, acc);
                acc = fmaf(__expf(-bwl * w3), f3, acc);
            }
            for (; i < m; ++i) {
                const int   s = __shfl(s_l, i, 32);
                const float w = __shfl(d2_l, i, 32);
                acc = fmaf(__expf(-bwl * w), hh[(size_t)s * H + lane], acc);
            }
        }

        // fc2 for this node (intra-wave lockstep)
        tmp[g][lane] = acc;
        float o_val = sb2[lane];
#pragma unroll
        for (int h = 0; h < H; ++h)
            o_val = fmaf(tmp[g][h], sW2[lane][h], o_val);
        stage[nl][lane] = o_val;
    }
    __syncthreads();

    // coalesced transposed write: out[batch, o, n0..n0+63]
    float* ob = out + (size_t)batch * COUT * N + n0;
#pragma unroll
    for (int i = 0; i < 8; ++i) {
        const int flat = i * 256 + tid;
        const int o = flat >> 6;
        const int j = flat & 63;
        ob[(size_t)o * N + j] = stage[j][o];
    }
}

// ---------------------------------------------------------------------------
extern "C" void kernel_launch(void* const* d_in, const int* in_sizes, int n_in,
                              void* d_out, int out_size, void* d_ws, size_t ws_size,
                              hipStream_t stream)
{
    const float* x    = (const float*)d_in[0];
    const float* grid = (const float*)d_in[1];
    const float* gw   = (const float*)d_in[2];
    const int*   es   = (const int*)d_in[3];
    const int*   ed   = (const int*)d_in[4];
    const float* W1   = (const float*)d_in[5];
    const float* b1   = (const float*)d_in[6];
    const float* W2   = (const float*)d_in[7];
    const float* b2   = (const float*)d_in[8];
    const float* bw   = (const float*)d_in[9];
    float* out = (float*)d_out;

    // workspace: hh 16 MB | gbucket 16 MB | gcur 8 KB   (33.57 MB total)
    char* w = (char*)d_ws;
    float*    hh      = (float*)(w);
    unsigned* gbucket = (unsigned*)(w + (size_t)NODES * H * 4);
    int*      gcur    = (int*)(w + (size_t)NODES * H * 4
                                 + (size_t)NBUCKETS * BUCKET_CAP * 4);

    hipMemsetAsync(gcur, 0, (size_t)NBUCKETS * sizeof(int), stream);

    k_fc1<<<NODES / 256, 256, 0, stream>>>(x, gw, W1, b1, bw, hh);
    k_bin<<<BIN_BLOCKS, BIN_THREADS, 0, stream>>>(es, ed, gcur, gbucket);
    k_gather2<<<NBUCKETS, 256, 0, stream>>>(grid, bw, hh, gbucket, gcur,
                                            W2, b2, out);
}